// Round 2
// baseline (89.694 us; speedup 1.0000x reference)
//
#include <hip/hip_runtime.h>

// Problem constants (B=1 throughout)
constexpr int kH  = 1024;
constexpr int kS  = 48;
constexpr int kNH = 32;
constexpr int kDH = 32;
constexpr float kSF = 0.2f;
// Output: [48, 48*32*32*32] f32. Row x = O[x] (32x32 = 1024 f32) tiled 1536 times.
constexpr int kRepsPerRow = kS * kNH;          // 1536
constexpr int kRowF4      = kRepsPerRow * 256; // 393216 float4 per output row

typedef float f32x4 __attribute__((ext_vector_type(4)));

__device__ __forceinline__ float4 ld4(const float* p) {
    return *reinterpret_cast<const float4*>(p);
}
__device__ __forceinline__ float dot4(float4 a, float4 b) {
    return a.x * b.x + a.y * b.y + a.z * b.z + a.w * b.w;
}

// ---------------------------------------------------------------------------
// Kernel 1: projections. qp = q@Wq.T + bq, kp = k@Wk.T + bk, vp = v@Wv.T + bv.
// One wave per (g, o): lane l owns K-elements {j*256 + l*4 .. +3}, j=0..3.
// Each wave computes qp[s,o] for all 48 s, butterfly-reduces, lane 0 stores.
// ---------------------------------------------------------------------------
__global__ __launch_bounds__(256) void proj_kernel(
    const float* __restrict__ q, const float* __restrict__ k, const float* __restrict__ v,
    const float* __restrict__ Wq, const float* __restrict__ bq,
    const float* __restrict__ Wk, const float* __restrict__ bk,
    const float* __restrict__ Wv, const float* __restrict__ bv,
    float* __restrict__ ws)
{
    const int wid  = blockIdx.x * 4 + (threadIdx.x >> 6); // 0..3071
    const int lane = threadIdx.x & 63;
    const int g = wid >> 10;     // 0=q,1=k,2=v
    const int o = wid & 1023;

    const float *X, *W, *Bv;
    if (g == 0)      { X = q; W = Wq; Bv = bq; }
    else if (g == 1) { X = k; W = Wk; Bv = bk; }
    else             { X = v; W = Wv; Bv = bv; }
    float* OUT = ws + g * (kS * kH);

    const float* wr = W + o * kH + lane * 4;
    const float4 w0 = ld4(wr);
    const float4 w1 = ld4(wr + 256);
    const float4 w2 = ld4(wr + 512);
    const float4 w3 = ld4(wr + 768);

    float acc[kS];
#pragma unroll
    for (int s = 0; s < kS; ++s) {
        const float* xr = X + s * kH + lane * 4;
        float4 x0 = ld4(xr);
        float4 x1 = ld4(xr + 256);
        float4 x2 = ld4(xr + 512);
        float4 x3 = ld4(xr + 768);
        acc[s] = dot4(x0, w0) + dot4(x1, w1) + dot4(x2, w2) + dot4(x3, w3);
    }
#pragma unroll
    for (int s = 0; s < kS; ++s) {
        float a = acc[s];
        a += __shfl_xor(a, 1);
        a += __shfl_xor(a, 2);
        a += __shfl_xor(a, 4);
        a += __shfl_xor(a, 8);
        a += __shfl_xor(a, 16);
        a += __shfl_xor(a, 32);
        acc[s] = a;
    }
    if (lane == 0) {
        const float bo = Bv[o];
#pragma unroll
        for (int s = 0; s < kS; ++s) OUT[s * kH + o] = acc[s] + bo;
    }
}

// ---------------------------------------------------------------------------
// Kernel 2: per-s attention core. One block (256 threads) per s.
//   _sq[n]   = (1/1024) * sum_d qp[s, n*32+d]^2
//   _sk[d,e] = (1/1024) * sum_n kp[s, n*32+d] * qp[s, n*32+e]
//   p[b,c]   = softmax_c( SF * |_sk[c,b] - _sq[b]| )       (stored transposed)
//   O[s,b,d] = sum_c p[b,c] * vp[s, c*32+d]
// ---------------------------------------------------------------------------
__global__ __launch_bounds__(256) void attn_kernel(
    const float* __restrict__ ws, float* __restrict__ O)
{
    const int s = blockIdx.x;
    const int t = threadIdx.x;

    __shared__ float qrow[kH];
    __shared__ float krow[kH];
    __shared__ float vrow[kH];
    __shared__ float sq[kNH];
    __shared__ float sk[kDH][kDH];  // sk[d][e]
    __shared__ float pT[kNH][kNH];  // pT[c][b] = p[b][c]

    const float* qp = ws;
    const float* kp = ws + kS * kH;
    const float* vp = ws + 2 * kS * kH;

    reinterpret_cast<float4*>(qrow)[t] = ld4(qp + s * kH + t * 4);
    reinterpret_cast<float4*>(krow)[t] = ld4(kp + s * kH + t * 4);
    reinterpret_cast<float4*>(vrow)[t] = ld4(vp + s * kH + t * 4);
    __syncthreads();

    if (t < kNH) {
        float a = 0.f;
#pragma unroll
        for (int d = 0; d < kDH; ++d) {
            float x = qrow[t * kDH + d];
            a += x * x;
        }
        sq[t] = a * (1.0f / 1024.0f);
    }
    {
        // _sk: thread t -> d = t>>3, e in { (t&7)*4 .. +3 }
        const int d = t >> 3;
        const int eq = t & 7;
        float4 a = {0.f, 0.f, 0.f, 0.f};
#pragma unroll
        for (int n = 0; n < kNH; ++n) {
            const float kv = krow[n * kDH + d];
            const float4 qv = reinterpret_cast<const float4*>(qrow)[n * 8 + eq];
            a.x += kv * qv.x; a.y += kv * qv.y; a.z += kv * qv.z; a.w += kv * qv.w;
        }
        const float sc = 1.0f / 1024.0f;
        a.x *= sc; a.y *= sc; a.z *= sc; a.w *= sc;
        *reinterpret_cast<float4*>(&sk[d][eq * 4]) = a;
    }
    __syncthreads();

    {
        // softmax over c for each b: thread t -> b = t>>3, c in {(t&7)*4 ..+3}
        const int b = t >> 3;
        const int c0 = (t & 7) * 4;
        const float s0 = sq[b];
        float v0 = kSF * fabsf(sk[c0 + 0][b] - s0);
        float v1 = kSF * fabsf(sk[c0 + 1][b] - s0);
        float v2 = kSF * fabsf(sk[c0 + 2][b] - s0);
        float v3 = kSF * fabsf(sk[c0 + 3][b] - s0);
        float m = fmaxf(fmaxf(v0, v1), fmaxf(v2, v3));
        m = fmaxf(m, __shfl_xor(m, 1));
        m = fmaxf(m, __shfl_xor(m, 2));
        m = fmaxf(m, __shfl_xor(m, 4));
        float e0 = __expf(v0 - m);
        float e1 = __expf(v1 - m);
        float e2 = __expf(v2 - m);
        float e3 = __expf(v3 - m);
        float sum = e0 + e1 + e2 + e3;
        sum += __shfl_xor(sum, 1);
        sum += __shfl_xor(sum, 2);
        sum += __shfl_xor(sum, 4);
        const float inv = 1.0f / sum;
        pT[c0 + 0][b] = e0 * inv;
        pT[c0 + 1][b] = e1 * inv;
        pT[c0 + 2][b] = e2 * inv;
        pT[c0 + 3][b] = e3 * inv;
    }
    __syncthreads();

    {
        // O[b][d]: thread t -> b = t>>3, d-quad = t&7
        const int b = t >> 3;
        const int dq = t & 7;
        float4 acc = {0.f, 0.f, 0.f, 0.f};
#pragma unroll
        for (int c = 0; c < kNH; ++c) {
            const float pv = pT[c][b];
            const float4 vv = reinterpret_cast<const float4*>(vrow)[c * 8 + dq];
            acc.x += pv * vv.x; acc.y += pv * vv.y; acc.z += pv * vv.z; acc.w += pv * vv.w;
        }
        reinterpret_cast<float4*>(O + s * kH + b * kDH)[dq] = acc;
    }
}

// ---------------------------------------------------------------------------
// Kernel 3: broadcast. Row x of output = O[x] (1024 f32) tiled 1536 times.
// Block = (x, rep-block of 16). Thread loads one f32x4 of O[x], stores 16x
// with nontemporal (streaming) stores — output is write-once, no reuse.
// ---------------------------------------------------------------------------
__global__ __launch_bounds__(256) void bcast_kernel(
    const float* __restrict__ O, float* __restrict__ out)
{
    const int x  = blockIdx.x / 96;   // output row
    const int rb = blockIdx.x % 96;   // which block of 16 repetitions
    const int t  = threadIdx.x;

    const f32x4 v = *reinterpret_cast<const f32x4*>(O + x * kH + t * 4);
    f32x4* dst = reinterpret_cast<f32x4*>(out)
               + (size_t)x * kRowF4 + (size_t)rb * (16 * 256) + t;
#pragma unroll
    for (int i = 0; i < 16; ++i) {
        __builtin_nontemporal_store(v, dst + i * 256);
    }
}

extern "C" void kernel_launch(void* const* d_in, const int* in_sizes, int n_in,
                              void* d_out, int out_size, void* d_ws, size_t ws_size,
                              hipStream_t stream)
{
    (void)in_sizes; (void)n_in; (void)out_size; (void)ws_size;
    const float* q  = (const float*)d_in[0];
    const float* k  = (const float*)d_in[1];
    const float* v  = (const float*)d_in[2];
    const float* Wq = (const float*)d_in[3];
    const float* bq = (const float*)d_in[4];
    const float* Wk = (const float*)d_in[5];
    const float* bk = (const float*)d_in[6];
    const float* Wv = (const float*)d_in[7];
    const float* bv = (const float*)d_in[8];

    float* ws  = (float*)d_ws;                 // qp | kp | vp | O
    float* O   = ws + 3 * kS * kH;
    float* out = (float*)d_out;

    proj_kernel<<<768, 256, 0, stream>>>(q, k, v, Wq, bq, Wk, bk, Wv, bv, ws);
    attn_kernel<<<kS, 256, 0, stream>>>(ws, O);
    bcast_kernel<<<kS * 96, 256, 0, stream>>>(O, out);
}